// Round 9
// baseline (188.169 us; speedup 1.0000x reference)
//
#include <hip/hip_runtime.h>
#include <hip/hip_bf16.h>

// NeuralTransformationCache, 3 kernels:
//   k_tbl8: table f32 -> fp8 e4m3 (x256); last block also packs weights
//   k_enc : one level per block (16 x 32 blocks), level staged in LDS once,
//           grid-stride points; enc[level][pt] fp8x4 dword
//   k_mlp : layer0 fp8 MFMA, layers 1-2 bf16 MFMA; hT XOR-swizzled (bank-floor
//           writes AND reads), resS overlays hT (32KB LDS -> 5 blocks/CU)
// Fallback fused kernel if ws too small.

#define LVL 16
#define TSZ 32768
#define PR1 2654435761u
#define PR2 805459861u
#define SUBS 32
#define STRIDE (SUBS * 1024)

typedef __attribute__((ext_vector_type(8))) short bf16x8;
typedef __attribute__((ext_vector_type(4))) float f32x4;
typedef __attribute__((ext_vector_type(2))) float f32x2;
typedef __attribute__((ext_vector_type(4))) unsigned short u16x4;
typedef __attribute__((ext_vector_type(2))) unsigned int u32x2;
typedef long long i64;

__device__ __forceinline__ unsigned short f2bf(float f) {
    return __builtin_bit_cast(unsigned short, __float2bfloat16(f));
}

// hT swizzled byte offset for element (kt, pt, j=0): row (kt,pt) stays 16B-contiguous.
// Writes: lanes spread over all 32 banks (floor). Reads (b128): stay at floor.
__device__ __forceinline__ int hswz(int kt, int pt) {
    return (kt * 4096 + pt * 16) ^ (((pt >> 2) & 3) << 5) ^ ((kt & 1) << 4);
}

// ---- fp8 e4m3fn (OCP) encode/decode, hw builtins with sw fallback ----
__device__ __forceinline__ unsigned f32x4_to_fp8x4(float f0, float f1, float f2, float f3) {
#if __has_builtin(__builtin_amdgcn_cvt_pk_fp8_f32)
    int u = 0;
    u = __builtin_amdgcn_cvt_pk_fp8_f32(f0, f1, u, false);
    u = __builtin_amdgcn_cvt_pk_fp8_f32(f2, f3, u, true);
    return (unsigned)u;
#else
    float ff[4] = { f0, f1, f2, f3 };
    unsigned u = 0;
    for (int k = 0; k < 4; ++k) {
        const float v = ff[k];
        const unsigned s = v < 0.f ? 1u : 0u;
        float av = fabsf(v);
        unsigned b;
        if (av < 6.103515625e-05f) {
            b = 0u;
        } else if (av < 0.015625f) {
            b = (unsigned)rintf(av * 512.f);
        } else {
            int e; float m = frexpf(av, &e);
            unsigned E = (unsigned)(e - 1 + 7);
            unsigned q = (unsigned)rintf(m * 16.f);
            if (q == 16u) { q = 8u; ++E; }
            b = (E << 3) | (q - 8u);
        }
        u |= ((s << 7) | b) << (8 * k);
    }
    return u;
#endif
}

__device__ __forceinline__ unsigned char f32_to_fp8(float v) {
    return (unsigned char)(f32x4_to_fp8x4(v, v, v, v) & 0xffu);
}

__device__ __forceinline__ void fp8x4_to_2f32x2(unsigned r, f32x2& lo, f32x2& hi) {
#if __has_builtin(__builtin_amdgcn_cvt_pk_f32_fp8)
    lo = __builtin_amdgcn_cvt_pk_f32_fp8((int)r, false);
    hi = __builtin_amdgcn_cvt_pk_f32_fp8((int)r, true);
#else
    float f[4];
#pragma unroll
    for (int k = 0; k < 4; ++k) {
        const unsigned b = (r >> (8 * k)) & 0xffu;
        const unsigned s = b >> 7, em = b & 0x7fu, e = em >> 3, m = em & 7u;
        float v;
        if (e) v = __builtin_bit_cast(float, ((e + 120u) << 23) | (m << 20));
        else   v = (float)m * 0.001953125f;
        f[k] = s ? -v : v;
    }
    lo = (f32x2){ f[0], f[1] };
    hi = (f32x2){ f[2], f[3] };
#endif
}

// ---------------- K0: table f32 -> fp8 (x256); last block packs weights ----------------
__global__ __launch_bounds__(256) void k_tbl8(
    const float* __restrict__ t, unsigned* __restrict__ o, int n4,
    const float* __restrict__ w0, const float* __restrict__ w1,
    const float* __restrict__ w2, char* __restrict__ wbase)
{
    const int g = blockIdx.x * 256 + threadIdx.x;
    if (g < n4) {
        const float4 a = reinterpret_cast<const float4*>(t)[g];
        o[g] = f32x4_to_fp8x4(a.x * 256.f, a.y * 256.f, a.z * 256.f, a.w * 256.f);
    }
    if (blockIdx.x == gridDim.x - 1) {
        const int tt = threadIdx.x;
        unsigned char*  wf8 = (unsigned char*)wbase;
        unsigned short* wf1 = (unsigned short*)(wbase + 4096);
        unsigned short* wf2 = (unsigned short*)(wbase + 4096 + 8192);
#pragma unroll
        for (int q = 0; q < 16; ++q) {
            const int s = q * 256 + tt;
            const int e = s & 7, f = s >> 3;
            const int ln = f & 63, ntkk = f >> 6;
            const int k = (ntkk & 1) * 32 + (ln >> 4) * 8 + e;
            const int n = (ntkk >> 1) * 16 + (ln & 15);
            wf8[s] = f32_to_fp8(w0[k * 64 + n]);
        }
#pragma unroll
        for (int q = 0; q < 16; ++q) {
            const int s = q * 256 + tt;
            const int e = s & 7, f = s >> 3;
            const int ln = f & 63, ntkk = f >> 6;
            const int k = (ntkk & 1) * 32 + (ln >> 4) * 8 + e;
            const int n = (ntkk >> 1) * 16 + (ln & 15);
            wf1[s] = f2bf(w1[k * 64 + n]);
        }
#pragma unroll
        for (int q = 0; q < 4; ++q) {
            const int s = q * 256 + tt;
            const int e = s & 7, f = s >> 3;
            const int ln = f & 63, kk = f >> 6;
            const int k = kk * 32 + (ln >> 4) * 8 + e;
            const int n = ln & 15;
            wf2[s] = (n < 8) ? f2bf(w2[k * 8 + n]) : (unsigned short)0;
        }
    }
}

// ---------------- K1: level-per-block encode, persistent LDS slice ----------------
__global__ __launch_bounds__(1024) void k_enc(
    const float* __restrict__ xyz, const float* __restrict__ bmin, const float* __restrict__ bmax,
    const unsigned* __restrict__ tbl8, float* __restrict__ out,
    unsigned* __restrict__ enc, int N, int Npad)
{
    __shared__ unsigned tabL[TSZ];     // 128KB: this block's level

    const int t   = threadIdx.x;
    const int l   = blockIdx.x & 15;
    const int sub = blockIdx.x >> 4;

    {
        const uint4* __restrict__ src = reinterpret_cast<const uint4*>(tbl8 + (size_t)l * TSZ);
        uint4* dst = reinterpret_cast<uint4*>(tabL);
#pragma unroll
        for (int j = 0; j < 8; ++j) dst[j * 1024 + t] = src[j * 1024 + t];
    }
    __syncthreads();

    const float bx0 = bmin[0], by0 = bmin[1], bz0 = bmin[2];
    const float iex = 1.f / (bmax[0] - bx0);
    const float iey = 1.f / (bmax[1] - by0);
    const float iez = 1.f / (bmax[2] - bz0);
    const float scale = 16.f * (float)(1u << l);
    unsigned* __restrict__ encL = enc + (size_t)l * Npad;
    const bool isL0 = (l == 0);

    const unsigned PR1_4 = PR1 << 2;   // shift folded into hash constants
    const unsigned PR2_4 = PR2 << 2;
    const unsigned M2 = (TSZ - 1u) << 2;

    int p = sub * 1024 + t;
    if (p < Npad) {
        int pc = p < N ? p : N - 1;
        float cxr = xyz[3 * pc + 0], cyr = xyz[3 * pc + 1], czr = xyz[3 * pc + 2];

        for (; p < Npad; ) {
            const int pn  = p + STRIDE;
            const int pnc = pn < N ? pn : N - 1;
            const float nxr = xyz[3 * pnc + 0];
            const float nyr = xyz[3 * pnc + 1];
            const float nzr = xyz[3 * pnc + 2];

            const float ccx = (cxr - bx0) * iex;
            const float ccy = (cyr - by0) * iey;
            const float ccz = (czr - bz0) * iez;
            if (isL0 && p < N) {
                const bool inside = (ccx >= 0.f) && (ccx <= 1.f) && (ccy >= 0.f) &&
                                    (ccy <= 1.f) && (ccz >= 0.f) && (ccz <= 1.f);
                out[p] = inside ? 1.f : 0.f;
            }
            const float x = fminf(fmaxf(ccx, 0.f), 1.f);
            const float y = fminf(fmaxf(ccy, 0.f), 1.f);
            const float z = fminf(fmaxf(ccz, 0.f), 1.f);

            const float px = x * scale, py = y * scale, pz = z * scale;
            const float fx = floorf(px), fy = floorf(py), fz = floorf(pz);
            const float rx = px - fx, ry = py - fy, rz = pz - fz;
            const unsigned ux = (unsigned)fx, uy = (unsigned)fy, uz = (unsigned)fz;

            // pre-shifted byte offsets: (a^b)<<2 = (a<<2)^(b<<2); mul const folded
            const unsigned ux4 = ux << 2;
            const unsigned hy4 = uy * PR1_4, hz4 = uz * PR2_4;
            const unsigned hxy2[4] = {
                (ux4        ^ hy4)           & M2,
                (ux4        ^ (hy4 + PR1_4)) & M2,
                ((ux4 + 4u) ^ hy4)           & M2,
                ((ux4 + 4u) ^ (hy4 + PR1_4)) & M2 };
            const unsigned hz2[2] = { hz4 & M2, (hz4 + PR2_4) & M2 };

            // packed weight products: 6 pk_mul instead of 12 scalar muls
            const float wx0 = 1.f - rx, wy0 = 1.f - ry, wz0 = 1.f - rz;
            const f32x2 wyp = { wy0, ry };
            const f32x2 wxyA = (f32x2){ wx0, wx0 } * wyp;   // c>>1 = 0,1
            const f32x2 wxyB = (f32x2){ rx,  rx  } * wyp;   // c>>1 = 2,3
            const f32x2 wz2 = { wz0, rz };
            const f32x2 w8[4] = {
                (f32x2){ wxyA[0], wxyA[0] } * wz2,   // c=0,1
                (f32x2){ wxyA[1], wxyA[1] } * wz2,   // c=2,3
                (f32x2){ wxyB[0], wxyB[0] } * wz2,   // c=4,5
                (f32x2){ wxyB[1], wxyB[1] } * wz2 }; // c=6,7

            unsigned r[8];
#pragma unroll
            for (int c = 0; c < 8; ++c)
                r[c] = *reinterpret_cast<const unsigned*>(
                    reinterpret_cast<const char*>(tabL) + (hxy2[c >> 1] ^ hz2[c & 1]));

            f32x2 a01 = { 0.f, 0.f }, a23 = { 0.f, 0.f };
#pragma unroll
            for (int c = 0; c < 8; ++c) {
                f32x2 lo, hi;
                fp8x4_to_2f32x2(r[c], lo, hi);
                const float w = w8[c >> 1][c & 1];
                const f32x2 w2 = { w, w };
                a01 += w2 * lo;
                a23 += w2 * hi;
            }

            const unsigned v = f32x4_to_fp8x4(a01[0], a01[1], a23[0], a23[1]);
            __builtin_nontemporal_store(v, encL + p);

            p = pn; cxr = nxr; cyr = nyr; czr = nzr;
        }
    }
}

// ---------------- K2: MLP — layer0 fp8 MFMA, layers 1-2 bf16 MFMA ----------------
__global__ __launch_bounds__(256) void k_mlp(
    const char* __restrict__ wbase, const unsigned* __restrict__ enc,
    float* __restrict__ out, int N, int Npad)
{
    __shared__ __align__(16) char hTb[32768];   // swizzled hT; resS overlays it

    const unsigned char*  wf8 = (const unsigned char*)wbase;
    const unsigned short* wf1 = (const unsigned short*)(wbase + 4096);
    const unsigned short* wf2 = (const unsigned short*)(wbase + 4096 + 8192);

    const int t = threadIdx.x, wv = t >> 6, ln = t & 63;
    const int col = ln & 15, g = ln >> 4;
    const int ptb = blockIdx.x * 256;
    const int i = ptb + t;

    // A0 fragments: levels (2j, 2j+1), j = kk*4+g (two dwords each)
    u32x2 a0[2][4];
#pragma unroll
    for (int kk = 0; kk < 2; ++kk)
#pragma unroll
        for (int mt = 0; mt < 4; ++mt) {
            const size_t pt = (size_t)ptb + wv * 64 + mt * 16 + col;
            const int j = kk * 4 + g;
            u32x2 a;
            a[0] = __builtin_nontemporal_load(enc + (size_t)(2 * j)     * Npad + pt);
            a[1] = __builtin_nontemporal_load(enc + (size_t)(2 * j + 1) * Npad + pt);
            a0[kk][mt] = a;
        }
    u32x2 b0[4][2];
#pragma unroll
    for (int nt = 0; nt < 4; ++nt)
#pragma unroll
        for (int kk = 0; kk < 2; ++kk)
            b0[nt][kk] = *reinterpret_cast<const u32x2*>(wf8 + ((nt * 2 + kk) * 64 + ln) * 8);

    f32x4 acc[4][4];
#pragma unroll
    for (int mt = 0; mt < 4; ++mt)
#pragma unroll
        for (int nt = 0; nt < 4; ++nt) acc[mt][nt] = (f32x4){0.f, 0.f, 0.f, 0.f};

#pragma unroll
    for (int kk = 0; kk < 2; ++kk)
#pragma unroll
        for (int nt = 0; nt < 4; ++nt)
#pragma unroll
            for (int mt = 0; mt < 4; ++mt)
                acc[mt][nt] = __builtin_amdgcn_mfma_f32_16x16x32_fp8_fp8(
                    __builtin_bit_cast(i64, a0[kk][mt]),
                    __builtin_bit_cast(i64, b0[nt][kk]), acc[mt][nt], 0, 0, 0);

    // relu + 1/256 -> hT bf16 (wave-private rows, swizzled addresses)
#pragma unroll
    for (int mt = 0; mt < 4; ++mt)
#pragma unroll
        for (int nt = 0; nt < 4; ++nt) {
            const int kt = nt * 2 + (col >> 3), j = col & 7;
#pragma unroll
            for (int r = 0; r < 4; ++r) {
                const int pt = wv * 64 + mt * 16 + g * 4 + r;
                *reinterpret_cast<unsigned short*>(hTb + hswz(kt, pt) + 2 * j) =
                    f2bf(fmaxf(acc[mt][nt][r], 0.f) * 0.00390625f);
            }
        }

    // ---- layer 1 (bf16) ----
    bf16x8 b1[4][2];
#pragma unroll
    for (int nt = 0; nt < 4; ++nt)
#pragma unroll
        for (int kk = 0; kk < 2; ++kk)
            b1[nt][kk] = *reinterpret_cast<const bf16x8*>(wf1 + ((nt * 2 + kk) * 64 + ln) * 8);

#pragma unroll
    for (int mt = 0; mt < 4; ++mt)
#pragma unroll
        for (int nt = 0; nt < 4; ++nt) acc[mt][nt] = (f32x4){0.f, 0.f, 0.f, 0.f};

#pragma unroll
    for (int kk = 0; kk < 2; ++kk) {
        bf16x8 a[4];
#pragma unroll
        for (int mt = 0; mt < 4; ++mt)
            a[mt] = *reinterpret_cast<const bf16x8*>(
                hTb + hswz(kk * 4 + g, wv * 64 + mt * 16 + col));
#pragma unroll
        for (int nt = 0; nt < 4; ++nt)
#pragma unroll
            for (int mt = 0; mt < 4; ++mt)
                acc[mt][nt] = __builtin_amdgcn_mfma_f32_16x16x32_bf16(a[mt], b1[nt][kk], acc[mt][nt], 0, 0, 0);
    }

#pragma unroll
    for (int mt = 0; mt < 4; ++mt)
#pragma unroll
        for (int nt = 0; nt < 4; ++nt) {
            const int kt = nt * 2 + (col >> 3), j = col & 7;
#pragma unroll
            for (int r = 0; r < 4; ++r) {
                const int pt = wv * 64 + mt * 16 + g * 4 + r;
                *reinterpret_cast<unsigned short*>(hTb + hswz(kt, pt) + 2 * j) =
                    f2bf(fmaxf(acc[mt][nt][r], 0.f));
            }
        }

    // ---- layer 2 (bf16) ----
    f32x4 acc2[4];
#pragma unroll
    for (int mt = 0; mt < 4; ++mt) acc2[mt] = (f32x4){0.f, 0.f, 0.f, 0.f};

#pragma unroll
    for (int kk = 0; kk < 2; ++kk) {
        const bf16x8 b2 = *reinterpret_cast<const bf16x8*>(wf2 + (kk * 64 + ln) * 8);
        bf16x8 a[4];
#pragma unroll
        for (int mt = 0; mt < 4; ++mt)
            a[mt] = *reinterpret_cast<const bf16x8*>(
                hTb + hswz(kk * 4 + g, wv * 64 + mt * 16 + col));
#pragma unroll
        for (int mt = 0; mt < 4; ++mt)
            acc2[mt] = __builtin_amdgcn_mfma_f32_16x16x32_bf16(a[mt], b2, acc2[mt], 0, 0, 0);
    }

    // resS overlays hTb -> barrier so all waves finish hT reads first
    __syncthreads();
    float* resS = reinterpret_cast<float*>(hTb);   // [256][8] f32, 8KB
    if (col < 8) {
#pragma unroll
        for (int mt = 0; mt < 4; ++mt)
#pragma unroll
            for (int r = 0; r < 4; ++r)
                resS[(wv * 64 + mt * 16 + g * 4 + r) * 8 + col] = acc2[mt][r];
    }
    __syncthreads();

    if (i < N) {
        const bool inside = (out[i] != 0.f);
        const f32x4 lo = *reinterpret_cast<f32x4*>(&resS[t * 8 + 0]);
        const f32x4 hi = *reinterpret_cast<f32x4*>(&resS[t * 8 + 4]);

        float* __restrict__ dxyz = out + N;
        dxyz[3 * i + 0] = inside ? lo.x : 0.f;
        dxyz[3 * i + 1] = inside ? lo.y : 0.f;
        dxyz[3 * i + 2] = inside ? lo.z : 0.f;

        float4* __restrict__ drot = reinterpret_cast<float4*>(out + 4 * (size_t)N);
        drot[i] = inside ? make_float4(lo.w, hi.x, hi.y, hi.z)
                         : make_float4(1.f, 0.f, 0.f, 0.f);
    }
}

// ---------------- Fallback: fused kernel (only if ws too small) ----------------
__global__ __launch_bounds__(256) void ntc_fused(
    const float* __restrict__ xyz, const float* __restrict__ bmin, const float* __restrict__ bmax,
    const float* __restrict__ table, const float* __restrict__ w0, const float* __restrict__ w1,
    const float* __restrict__ w2, float* __restrict__ out, int N)
{
    __shared__ unsigned short encT[8 * 256 * 8];
    __shared__ unsigned short w0t[64 * 64];
    __shared__ unsigned short w1t[64 * 64];
    __shared__ unsigned short w2t[16 * 64];

    const int t = threadIdx.x, wv = t >> 6, ln = t & 63;
    const int col = ln & 15, g = ln >> 4;

#pragma unroll
    for (int it = 0; it < 16; ++it) {
        const int idx = it * 256 + t;
        const int k = idx >> 6, n = idx & 63;
        w0t[n * 64 + k] = f2bf(w0[idx]);
        w1t[n * 64 + k] = f2bf(w1[idx]);
    }
#pragma unroll
    for (int q = 0; q < 4; ++q) {
        const int idx = t * 4 + q;
        const int n = idx >> 6, k = idx & 63;
        w2t[idx] = (n < 8) ? f2bf(w2[k * 8 + n]) : (unsigned short)0;
    }

    const int i = blockIdx.x * 256 + t;
    const int ic = (i < N) ? i : (N - 1);
    const float bx0 = bmin[0], by0 = bmin[1], bz0 = bmin[2];
    const float ex = bmax[0] - bx0, ey = bmax[1] - by0, ez = bmax[2] - bz0;
    const float cx = (xyz[3 * ic + 0] - bx0) / ex;
    const float cy = (xyz[3 * ic + 1] - by0) / ey;
    const float cz = (xyz[3 * ic + 2] - bz0) / ez;
    const bool inside = (cx >= 0.f) && (cx <= 1.f) && (cy >= 0.f) && (cy <= 1.f) &&
                        (cz >= 0.f) && (cz <= 1.f);
    const float x = fminf(fmaxf(cx, 0.f), 1.f);
    const float y = fminf(fmaxf(cy, 0.f), 1.f);
    const float z = fminf(fmaxf(cz, 0.f), 1.f);
    const float4* __restrict__ tab = reinterpret_cast<const float4*>(table);

    for (int l = 0; l < LVL; ++l) {
        const float scale = 16.f * (float)(1u << l);
        const float px = x * scale, py = y * scale, pz = z * scale;
        const float fx = floorf(px), fy = floorf(py), fz = floorf(pz);
        const float rx = px - fx, ry = py - fy, rz = pz - fz;
        const unsigned ux = (unsigned)fx, uy = (unsigned)fy, uz = (unsigned)fz;
        const unsigned hx[2] = { ux, ux + 1u };
        const unsigned hy[2] = { uy * PR1, (uy + 1u) * PR1 };
        const unsigned hz[2] = { uz * PR2, (uz + 1u) * PR2 };
        const float wx[2] = { 1.f - rx, rx };
        const float wy[2] = { 1.f - ry, ry };
        const float wz[2] = { 1.f - rz, rz };
        float a0 = 0.f, a1 = 0.f, a2 = 0.f, a3 = 0.f;
#pragma unroll
        for (int c = 0; c < 8; ++c) {
            const int ox = (c >> 2) & 1, oy = (c >> 1) & 1, oz = c & 1;
            const unsigned idx = (hx[ox] ^ hy[oy] ^ hz[oz]) & (TSZ - 1u);
            const float4 f4 = tab[l * TSZ + idx];
            const float w = wx[ox] * wy[oy] * wz[oz];
            a0 = fmaf(w, f4.x, a0); a1 = fmaf(w, f4.y, a1);
            a2 = fmaf(w, f4.z, a2); a3 = fmaf(w, f4.w, a3);
        }
        u16x4 v = { f2bf(a0), f2bf(a1), f2bf(a2), f2bf(a3) };
        *reinterpret_cast<u16x4*>(&encT[(l >> 1) * 2048 + t * 8 + (l & 1) * 4]) = v;
    }
    __syncthreads();

    f32x4 acc[4][4];
#pragma unroll
    for (int mt = 0; mt < 4; ++mt)
#pragma unroll
        for (int nt = 0; nt < 4; ++nt) acc[mt][nt] = (f32x4){0.f, 0.f, 0.f, 0.f};
#pragma unroll
    for (int kk = 0; kk < 2; ++kk) {
        bf16x8 a[4];
#pragma unroll
        for (int mt = 0; mt < 4; ++mt)
            a[mt] = *reinterpret_cast<bf16x8*>(&encT[(kk * 4 + g) * 2048 + (wv * 64 + mt * 16 + col) * 8]);
#pragma unroll
        for (int nt = 0; nt < 4; ++nt) {
            bf16x8 b = *reinterpret_cast<bf16x8*>(&w0t[(nt * 16 + col) * 64 + kk * 32 + g * 8]);
#pragma unroll
            for (int mt = 0; mt < 4; ++mt)
                acc[mt][nt] = __builtin_amdgcn_mfma_f32_16x16x32_bf16(a[mt], b, acc[mt][nt], 0, 0, 0);
        }
    }
    __syncthreads();
#pragma unroll
    for (int mt = 0; mt < 4; ++mt)
#pragma unroll
        for (int nt = 0; nt < 4; ++nt) {
            const int kt = nt * 2 + (col >> 3), j = col & 7;
#pragma unroll
            for (int r = 0; r < 4; ++r)
                encT[kt * 2048 + (wv * 64 + mt * 16 + g * 4 + r) * 8 + j] = f2bf(fmaxf(acc[mt][nt][r], 0.f));
        }
    __syncthreads();
#pragma unroll
    for (int mt = 0; mt < 4; ++mt)
#pragma unroll
        for (int nt = 0; nt < 4; ++nt) acc[mt][nt] = (f32x4){0.f, 0.f, 0.f, 0.f};
#pragma unroll
    for (int kk = 0; kk < 2; ++kk) {
        bf16x8 a[4];
#pragma unroll
        for (int mt = 0; mt < 4; ++mt)
            a[mt] = *reinterpret_cast<bf16x8*>(&encT[(kk * 4 + g) * 2048 + (wv * 64 + mt * 16 + col) * 8]);
#pragma unroll
        for (int nt = 0; nt < 4; ++nt) {
            bf16x8 b = *reinterpret_cast<bf16x8*>(&w1t[(nt * 16 + col) * 64 + kk * 32 + g * 8]);
#pragma unroll
            for (int mt = 0; mt < 4; ++mt)
                acc[mt][nt] = __builtin_amdgcn_mfma_f32_16x16x32_bf16(a[mt], b, acc[mt][nt], 0, 0, 0);
        }
    }
    __syncthreads();
#pragma unroll
    for (int mt = 0; mt < 4; ++mt)
#pragma unroll
        for (int nt = 0; nt < 4; ++nt) {
            const int kt = nt * 2 + (col >> 3), j = col & 7;
#pragma unroll
            for (int r = 0; r < 4; ++r)
                encT[kt * 2048 + (wv * 64 + mt * 16 + g * 4 + r) * 8 + j] = f2bf(fmaxf(acc[mt][nt][r], 0.f));
        }
    __syncthreads();
    f32x4 acc2[4];
#pragma unroll
    for (int mt = 0; mt < 4; ++mt) acc2[mt] = (f32x4){0.f, 0.f, 0.f, 0.f};
#pragma unroll
    for (int kk = 0; kk < 2; ++kk) {
        bf16x8 a[4];
#pragma unroll
        for (int mt = 0; mt < 4; ++mt)
            a[mt] = *reinterpret_cast<bf16x8*>(&encT[(kk * 4 + g) * 2048 + (wv * 64 + mt * 16 + col) * 8]);
        bf16x8 b = *reinterpret_cast<bf16x8*>(&w2t[col * 64 + kk * 32 + g * 8]);
#pragma unroll
        for (int mt = 0; mt < 4; ++mt)
            acc2[mt] = __builtin_amdgcn_mfma_f32_16x16x32_bf16(a[mt], b, acc2[mt], 0, 0, 0);
    }
    __syncthreads();
    float* res = reinterpret_cast<float*>(encT);
    if (col < 8) {
#pragma unroll
        for (int mt = 0; mt < 4; ++mt)
#pragma unroll
            for (int r = 0; r < 4; ++r)
                res[(wv * 64 + mt * 16 + g * 4 + r) * 8 + col] = acc2[mt][r];
    }
    __syncthreads();
    if (i < N) {
        const f32x4 lo = *reinterpret_cast<f32x4*>(&res[t * 8 + 0]);
        const f32x4 hi = *reinterpret_cast<f32x4*>(&res[t * 8 + 4]);
        out[i] = inside ? 1.f : 0.f;
        float* __restrict__ dxyz = out + N;
        dxyz[3 * i + 0] = inside ? lo.x : 0.f;
        dxyz[3 * i + 1] = inside ? lo.y : 0.f;
        dxyz[3 * i + 2] = inside ? lo.z : 0.f;
        float4* __restrict__ drot = reinterpret_cast<float4*>(out + 4 * (size_t)N);
        drot[i] = inside ? make_float4(lo.w, hi.x, hi.y, hi.z)
                         : make_float4(1.f, 0.f, 0.f, 0.f);
    }
}

extern "C" void kernel_launch(void* const* d_in, const int* in_sizes, int n_in,
                              void* d_out, int out_size, void* d_ws, size_t ws_size,
                              hipStream_t stream) {
    const float* xyz   = (const float*)d_in[0];
    const float* bmin  = (const float*)d_in[1];
    const float* bmax  = (const float*)d_in[2];
    const float* table = (const float*)d_in[3];
    const float* w0    = (const float*)d_in[4];
    const float* w1    = (const float*)d_in[5];
    const float* w2    = (const float*)d_in[6];
    float* out = (float*)d_out;

    const int N = in_sizes[0] / 3;
    const int nb = (N + 255) / 256;
    const int Npad = ((N + 4095) / 4096) * 4096;
    const int tblElems = in_sizes[3];

    size_t offW = ((size_t)tblElems + 63) & ~(size_t)63;
    size_t offEnc = (offW + 14336 + 255) & ~(size_t)255;
    size_t need = offEnc + (size_t)Npad * 64;

    if (ws_size >= need) {
        unsigned* tbl8 = (unsigned*)d_ws;
        char* wbase    = (char*)d_ws + offW;
        unsigned* enc  = (unsigned*)((char*)d_ws + offEnc);
        const int n4 = tblElems / 4;
        k_tbl8<<<(n4 + 255) / 256, 256, 0, stream>>>(table, tbl8, n4, w0, w1, w2, wbase);
        k_enc<<<16 * SUBS, 1024, 0, stream>>>(xyz, bmin, bmax, tbl8, out, enc, N, Npad);
        k_mlp<<<nb, 256, 0, stream>>>(wbase, enc, out, N, Npad);
    } else {
        ntc_fused<<<nb, 256, 0, stream>>>(xyz, bmin, bmax, table, w0, w1, w2, out, N);
    }
}

// Round 10
// 173.388 us; speedup vs baseline: 1.0853x; 1.0853x over previous
//
#include <hip/hip_runtime.h>
#include <hip/hip_bf16.h>

// NeuralTransformationCache, 2 kernels:
//   k_enc : one level per block (16 levels x 16 sub-blocks = 256 blocks, 1/CU).
//           Each block converts ITS level slice f32->fp8(x256) while staging to
//           LDS (no separate table-conversion kernel). Block 255 also packs the
//           MLP weights into MFMA-fragment order. Grid-stride over points;
//           enc[level][pt] fp8x4 dword output.
//   k_mlp : layer0 fp8 MFMA (1/256 folded into ReLU), layers 1-2 bf16 MFMA.
// Fallback fused kernel if ws too small.

#define LVL 16
#define TSZ 32768
#define PR1 2654435761u
#define PR2 805459861u
#define SUBS 16
#define STRIDE (SUBS * 1024)

typedef __attribute__((ext_vector_type(8))) short bf16x8;
typedef __attribute__((ext_vector_type(4))) float f32x4;
typedef __attribute__((ext_vector_type(2))) float f32x2;
typedef __attribute__((ext_vector_type(4))) unsigned short u16x4;
typedef __attribute__((ext_vector_type(2))) unsigned int u32x2;
typedef long long i64;

__device__ __forceinline__ unsigned short f2bf(float f) {
    return __builtin_bit_cast(unsigned short, __float2bfloat16(f));
}

// ---- fp8 e4m3fn (OCP) encode/decode, hw builtins with sw fallback ----
__device__ __forceinline__ unsigned f32x4_to_fp8x4(float f0, float f1, float f2, float f3) {
#if __has_builtin(__builtin_amdgcn_cvt_pk_fp8_f32)
    int u = 0;
    u = __builtin_amdgcn_cvt_pk_fp8_f32(f0, f1, u, false);
    u = __builtin_amdgcn_cvt_pk_fp8_f32(f2, f3, u, true);
    return (unsigned)u;
#else
    float ff[4] = { f0, f1, f2, f3 };
    unsigned u = 0;
    for (int k = 0; k < 4; ++k) {
        const float v = ff[k];
        const unsigned s = v < 0.f ? 1u : 0u;
        float av = fabsf(v);
        unsigned b;
        if (av < 6.103515625e-05f) {
            b = 0u;
        } else if (av < 0.015625f) {
            b = (unsigned)rintf(av * 512.f);
        } else {
            int e; float m = frexpf(av, &e);
            unsigned E = (unsigned)(e - 1 + 7);
            unsigned q = (unsigned)rintf(m * 16.f);
            if (q == 16u) { q = 8u; ++E; }
            b = (E << 3) | (q - 8u);
        }
        u |= ((s << 7) | b) << (8 * k);
    }
    return u;
#endif
}

__device__ __forceinline__ unsigned char f32_to_fp8(float v) {
    return (unsigned char)(f32x4_to_fp8x4(v, v, v, v) & 0xffu);
}

__device__ __forceinline__ void fp8x4_to_2f32x2(unsigned r, f32x2& lo, f32x2& hi) {
#if __has_builtin(__builtin_amdgcn_cvt_pk_f32_fp8)
    lo = __builtin_amdgcn_cvt_pk_f32_fp8((int)r, false);
    hi = __builtin_amdgcn_cvt_pk_f32_fp8((int)r, true);
#else
    float f[4];
#pragma unroll
    for (int k = 0; k < 4; ++k) {
        const unsigned b = (r >> (8 * k)) & 0xffu;
        const unsigned s = b >> 7, em = b & 0x7fu, e = em >> 3, m = em & 7u;
        float v;
        if (e) v = __builtin_bit_cast(float, ((e + 120u) << 23) | (m << 20));
        else   v = (float)m * 0.001953125f;
        f[k] = s ? -v : v;
    }
    lo = (f32x2){ f[0], f[1] };
    hi = (f32x2){ f[2], f[3] };
#endif
}

// ---------------- K1: level-per-block encode; staging converts f32->fp8 ----------------
// wbase layout (bytes): wf8[4096] (w0 fp8 frags) | wf1[8192] (w1 bf16 frags) | wf2[2048]
__global__ __launch_bounds__(1024) void k_enc(
    const float* __restrict__ xyz, const float* __restrict__ bmin, const float* __restrict__ bmax,
    const float* __restrict__ table, float* __restrict__ out,
    unsigned* __restrict__ enc, int N, int Npad,
    const float* __restrict__ w0, const float* __restrict__ w1,
    const float* __restrict__ w2, char* __restrict__ wbase)
{
    __shared__ unsigned tabL[TSZ];     // 128KB: this block's level, fp8x4 per entry

    const int t   = threadIdx.x;
    const int l   = blockIdx.x & 15;
    const int sub = blockIdx.x >> 4;

    {   // stage + convert: 512KB f32 (mostly L3-hit) -> 128KB fp8 LDS
        const float4* __restrict__ src =
            reinterpret_cast<const float4*>(table + (size_t)l * TSZ * 4);
#pragma unroll 4
        for (int j = 0; j < 32; ++j) {
            const int idx = j * 1024 + t;
            const float4 a = src[idx];
            tabL[idx] = f32x4_to_fp8x4(a.x * 256.f, a.y * 256.f, a.z * 256.f, a.w * 256.f);
        }
    }

    // one block packs the MLP weights (done before k_mlp launches; stream-ordered)
    if (blockIdx.x == 16 * SUBS - 1 && t < 256) {
        unsigned char*  wf8 = (unsigned char*)wbase;
        unsigned short* wf1 = (unsigned short*)(wbase + 4096);
        unsigned short* wf2 = (unsigned short*)(wbase + 4096 + 8192);
#pragma unroll
        for (int q = 0; q < 16; ++q) {
            const int s = q * 256 + t;
            const int e = s & 7, f = s >> 3;
            const int ln = f & 63, ntkk = f >> 6;
            const int k = (ntkk & 1) * 32 + (ln >> 4) * 8 + e;
            const int n = (ntkk >> 1) * 16 + (ln & 15);
            wf8[s] = f32_to_fp8(w0[k * 64 + n]);
            wf1[s] = f2bf(w1[k * 64 + n]);
        }
#pragma unroll
        for (int q = 0; q < 4; ++q) {
            const int s = q * 256 + t;
            const int e = s & 7, f = s >> 3;
            const int ln = f & 63, kk = f >> 6;
            const int k = kk * 32 + (ln >> 4) * 8 + e;
            const int n = ln & 15;
            wf2[s] = (n < 8) ? f2bf(w2[k * 8 + n]) : (unsigned short)0;
        }
    }
    __syncthreads();

    const float bx0 = bmin[0], by0 = bmin[1], bz0 = bmin[2];
    const float iex = 1.f / (bmax[0] - bx0);
    const float iey = 1.f / (bmax[1] - by0);
    const float iez = 1.f / (bmax[2] - bz0);
    const float scale = 16.f * (float)(1u << l);
    unsigned* __restrict__ encL = enc + (size_t)l * Npad;
    const bool isL0 = (l == 0);

    const unsigned PR1_4 = PR1 << 2;
    const unsigned PR2_4 = PR2 << 2;
    const unsigned M2 = (TSZ - 1u) << 2;

    int p = sub * 1024 + t;
    if (p < Npad) {
        int pc = p < N ? p : N - 1;
        float cxr = xyz[3 * pc + 0], cyr = xyz[3 * pc + 1], czr = xyz[3 * pc + 2];

        for (; p < Npad; ) {
            const int pn  = p + STRIDE;
            const int pnc = (pn < N) ? pn : (N - 1);
            const float nxr = xyz[3 * pnc + 0];
            const float nyr = xyz[3 * pnc + 1];
            const float nzr = xyz[3 * pnc + 2];

            const float ccx = (cxr - bx0) * iex;
            const float ccy = (cyr - by0) * iey;
            const float ccz = (czr - bz0) * iez;
            if (isL0 && p < N) {
                const bool inside = (ccx >= 0.f) && (ccx <= 1.f) && (ccy >= 0.f) &&
                                    (ccy <= 1.f) && (ccz >= 0.f) && (ccz <= 1.f);
                out[p] = inside ? 1.f : 0.f;
            }
            const float x = fminf(fmaxf(ccx, 0.f), 1.f);
            const float y = fminf(fmaxf(ccy, 0.f), 1.f);
            const float z = fminf(fmaxf(ccz, 0.f), 1.f);

            const float px = x * scale, py = y * scale, pz = z * scale;
            const float fx = floorf(px), fy = floorf(py), fz = floorf(pz);
            const float rx = px - fx, ry = py - fy, rz = pz - fz;
            const unsigned ux = (unsigned)fx, uy = (unsigned)fy, uz = (unsigned)fz;

            const unsigned ux4 = ux << 2;
            const unsigned hy4 = uy * PR1_4, hz4 = uz * PR2_4;
            const unsigned hxy2[4] = {
                (ux4        ^ hy4)           & M2,
                (ux4        ^ (hy4 + PR1_4)) & M2,
                ((ux4 + 4u) ^ hy4)           & M2,
                ((ux4 + 4u) ^ (hy4 + PR1_4)) & M2 };
            const unsigned hz2[2] = { hz4 & M2, (hz4 + PR2_4) & M2 };

            const float wx0 = 1.f - rx, wy0 = 1.f - ry, wz0 = 1.f - rz;
            const f32x2 wyp = { wy0, ry };
            const f32x2 wxyA = (f32x2){ wx0, wx0 } * wyp;
            const f32x2 wxyB = (f32x2){ rx,  rx  } * wyp;
            const f32x2 wz2 = { wz0, rz };
            const f32x2 w8[4] = {
                (f32x2){ wxyA[0], wxyA[0] } * wz2,
                (f32x2){ wxyA[1], wxyA[1] } * wz2,
                (f32x2){ wxyB[0], wxyB[0] } * wz2,
                (f32x2){ wxyB[1], wxyB[1] } * wz2 };

            unsigned r[8];
#pragma unroll
            for (int c = 0; c < 8; ++c)
                r[c] = *reinterpret_cast<const unsigned*>(
                    reinterpret_cast<const char*>(tabL) + (hxy2[c >> 1] ^ hz2[c & 1]));

            f32x2 a01 = { 0.f, 0.f }, a23 = { 0.f, 0.f };
#pragma unroll
            for (int c = 0; c < 8; ++c) {
                f32x2 lo, hi;
                fp8x4_to_2f32x2(r[c], lo, hi);
                const float w = w8[c >> 1][c & 1];
                const f32x2 w2 = { w, w };
                a01 += w2 * lo;
                a23 += w2 * hi;
            }

            const unsigned v = f32x4_to_fp8x4(a01[0], a01[1], a23[0], a23[1]);
            __builtin_nontemporal_store(v, encL + p);

            p = pn; cxr = nxr; cyr = nyr; czr = nzr;
        }
    }
}

// ---------------- K2: MLP — layer0 fp8 MFMA, layers 1-2 bf16 MFMA (R8 version) ----------------
__global__ __launch_bounds__(256) void k_mlp(
    const char* __restrict__ wbase, const unsigned* __restrict__ enc,
    float* __restrict__ out, int N, int Npad)
{
    __shared__ unsigned short hT[8 * 256 * 8];  // 32KB
    __shared__ float resS[256 * 8];             // 8KB

    const unsigned char*  wf8 = (const unsigned char*)wbase;
    const unsigned short* wf1 = (const unsigned short*)(wbase + 4096);
    const unsigned short* wf2 = (const unsigned short*)(wbase + 4096 + 8192);

    const int t = threadIdx.x, wv = t >> 6, ln = t & 63;
    const int col = ln & 15, g = ln >> 4;
    const int ptb = blockIdx.x * 256;
    const int i = ptb + t;

    // A0 fragments: levels (2j, 2j+1), j = kk*4+g (two dwords each)
    u32x2 a0[2][4];
#pragma unroll
    for (int kk = 0; kk < 2; ++kk)
#pragma unroll
        for (int mt = 0; mt < 4; ++mt) {
            const size_t pt = (size_t)ptb + wv * 64 + mt * 16 + col;
            const int j = kk * 4 + g;
            u32x2 a;
            a[0] = __builtin_nontemporal_load(enc + (size_t)(2 * j)     * Npad + pt);
            a[1] = __builtin_nontemporal_load(enc + (size_t)(2 * j + 1) * Npad + pt);
            a0[kk][mt] = a;
        }
    u32x2 b0[4][2];
#pragma unroll
    for (int nt = 0; nt < 4; ++nt)
#pragma unroll
        for (int kk = 0; kk < 2; ++kk)
            b0[nt][kk] = *reinterpret_cast<const u32x2*>(wf8 + ((nt * 2 + kk) * 64 + ln) * 8);

    f32x4 acc[4][4];
#pragma unroll
    for (int mt = 0; mt < 4; ++mt)
#pragma unroll
        for (int nt = 0; nt < 4; ++nt) acc[mt][nt] = (f32x4){0.f, 0.f, 0.f, 0.f};

#pragma unroll
    for (int kk = 0; kk < 2; ++kk)
#pragma unroll
        for (int nt = 0; nt < 4; ++nt)
#pragma unroll
            for (int mt = 0; mt < 4; ++mt)
                acc[mt][nt] = __builtin_amdgcn_mfma_f32_16x16x32_fp8_fp8(
                    __builtin_bit_cast(i64, a0[kk][mt]),
                    __builtin_bit_cast(i64, b0[nt][kk]), acc[mt][nt], 0, 0, 0);

    // relu + 1/256 -> hT bf16 (wave-private rows)
#pragma unroll
    for (int mt = 0; mt < 4; ++mt)
#pragma unroll
        for (int nt = 0; nt < 4; ++nt) {
            const int kt = nt * 2 + (col >> 3), j = col & 7;
#pragma unroll
            for (int r = 0; r < 4; ++r)
                hT[kt * 2048 + (wv * 64 + mt * 16 + g * 4 + r) * 8 + j] =
                    f2bf(fmaxf(acc[mt][nt][r], 0.f) * 0.00390625f);
        }

    // ---- layer 1 (bf16) ----
    bf16x8 b1[4][2];
#pragma unroll
    for (int nt = 0; nt < 4; ++nt)
#pragma unroll
        for (int kk = 0; kk < 2; ++kk)
            b1[nt][kk] = *reinterpret_cast<const bf16x8*>(wf1 + ((nt * 2 + kk) * 64 + ln) * 8);

#pragma unroll
    for (int mt = 0; mt < 4; ++mt)
#pragma unroll
        for (int nt = 0; nt < 4; ++nt) acc[mt][nt] = (f32x4){0.f, 0.f, 0.f, 0.f};

#pragma unroll
    for (int kk = 0; kk < 2; ++kk) {
        bf16x8 a[4];
#pragma unroll
        for (int mt = 0; mt < 4; ++mt)
            a[mt] = *reinterpret_cast<bf16x8*>(
                &hT[(kk * 4 + g) * 2048 + (wv * 64 + mt * 16 + col) * 8]);
#pragma unroll
        for (int nt = 0; nt < 4; ++nt)
#pragma unroll
            for (int mt = 0; mt < 4; ++mt)
                acc[mt][nt] = __builtin_amdgcn_mfma_f32_16x16x32_bf16(a[mt], b1[nt][kk], acc[mt][nt], 0, 0, 0);
    }

#pragma unroll
    for (int mt = 0; mt < 4; ++mt)
#pragma unroll
        for (int nt = 0; nt < 4; ++nt) {
            const int kt = nt * 2 + (col >> 3), j = col & 7;
#pragma unroll
            for (int r = 0; r < 4; ++r)
                hT[kt * 2048 + (wv * 64 + mt * 16 + g * 4 + r) * 8 + j] =
                    f2bf(fmaxf(acc[mt][nt][r], 0.f));
        }

    // ---- layer 2 (bf16) ----
    f32x4 acc2[4];
#pragma unroll
    for (int mt = 0; mt < 4; ++mt) acc2[mt] = (f32x4){0.f, 0.f, 0.f, 0.f};

#pragma unroll
    for (int kk = 0; kk < 2; ++kk) {
        const bf16x8 b2 = *reinterpret_cast<const bf16x8*>(wf2 + (kk * 64 + ln) * 8);
        bf16x8 a[4];
#pragma unroll
        for (int mt = 0; mt < 4; ++mt)
            a[mt] = *reinterpret_cast<bf16x8*>(
                &hT[(kk * 4 + g) * 2048 + (wv * 64 + mt * 16 + col) * 8]);
#pragma unroll
        for (int mt = 0; mt < 4; ++mt)
            acc2[mt] = __builtin_amdgcn_mfma_f32_16x16x32_bf16(a[mt], b2, acc2[mt], 0, 0, 0);
    }

    if (col < 8) {
#pragma unroll
        for (int mt = 0; mt < 4; ++mt)
#pragma unroll
            for (int r = 0; r < 4; ++r)
                resS[(wv * 64 + mt * 16 + g * 4 + r) * 8 + col] = acc2[mt][r];
    }
    __syncthreads();

    if (i < N) {
        const bool inside = (out[i] != 0.f);
        const f32x4 lo = *reinterpret_cast<f32x4*>(&resS[t * 8 + 0]);
        const f32x4 hi = *reinterpret_cast<f32x4*>(&resS[t * 8 + 4]);

        float* __restrict__ dxyz = out + N;
        dxyz[3 * i + 0] = inside ? lo.x : 0.f;
        dxyz[3 * i + 1] = inside ? lo.y : 0.f;
        dxyz[3 * i + 2] = inside ? lo.z : 0.f;

        float4* __restrict__ drot = reinterpret_cast<float4*>(out + 4 * (size_t)N);
        drot[i] = inside ? make_float4(lo.w, hi.x, hi.y, hi.z)
                         : make_float4(1.f, 0.f, 0.f, 0.f);
    }
}

// ---------------- Fallback: fused kernel (only if ws too small) ----------------
__global__ __launch_bounds__(256) void ntc_fused(
    const float* __restrict__ xyz, const float* __restrict__ bmin, const float* __restrict__ bmax,
    const float* __restrict__ table, const float* __restrict__ w0, const float* __restrict__ w1,
    const float* __restrict__ w2, float* __restrict__ out, int N)
{
    __shared__ unsigned short encT[8 * 256 * 8];
    __shared__ unsigned short w0t[64 * 64];
    __shared__ unsigned short w1t[64 * 64];
    __shared__ unsigned short w2t[16 * 64];

    const int t = threadIdx.x, wv = t >> 6, ln = t & 63;
    const int col = ln & 15, g = ln >> 4;

#pragma unroll
    for (int it = 0; it < 16; ++it) {
        const int idx = it * 256 + t;
        const int k = idx >> 6, n = idx & 63;
        w0t[n * 64 + k] = f2bf(w0[idx]);
        w1t[n * 64 + k] = f2bf(w1[idx]);
    }
#pragma unroll
    for (int q = 0; q < 4; ++q) {
        const int idx = t * 4 + q;
        const int n = idx >> 6, k = idx & 63;
        w2t[idx] = (n < 8) ? f2bf(w2[k * 8 + n]) : (unsigned short)0;
    }

    const int i = blockIdx.x * 256 + t;
    const int ic = (i < N) ? i : (N - 1);
    const float bx0 = bmin[0], by0 = bmin[1], bz0 = bmin[2];
    const float ex = bmax[0] - bx0, ey = bmax[1] - by0, ez = bmax[2] - bz0;
    const float cx = (xyz[3 * ic + 0] - bx0) / ex;
    const float cy = (xyz[3 * ic + 1] - by0) / ey;
    const float cz = (xyz[3 * ic + 2] - bz0) / ez;
    const bool inside = (cx >= 0.f) && (cx <= 1.f) && (cy >= 0.f) && (cy <= 1.f) &&
                        (cz >= 0.f) && (cz <= 1.f);
    const float x = fminf(fmaxf(cx, 0.f), 1.f);
    const float y = fminf(fmaxf(cy, 0.f), 1.f);
    const float z = fminf(fmaxf(cz, 0.f), 1.f);
    const float4* __restrict__ tab = reinterpret_cast<const float4*>(table);

    for (int l = 0; l < LVL; ++l) {
        const float scale = 16.f * (float)(1u << l);
        const float px = x * scale, py = y * scale, pz = z * scale;
        const float fx = floorf(px), fy = floorf(py), fz = floorf(pz);
        const float rx = px - fx, ry = py - fy, rz = pz - fz;
        const unsigned ux = (unsigned)fx, uy = (unsigned)fy, uz = (unsigned)fz;
        const unsigned hx[2] = { ux, ux + 1u };
        const unsigned hy[2] = { uy * PR1, (uy + 1u) * PR1 };
        const unsigned hz[2] = { uz * PR2, (uz + 1u) * PR2 };
        const float wx[2] = { 1.f - rx, rx };
        const float wy[2] = { 1.f - ry, ry };
        const float wz[2] = { 1.f - rz, rz };
        float a0 = 0.f, a1 = 0.f, a2 = 0.f, a3 = 0.f;
#pragma unroll
        for (int c = 0; c < 8; ++c) {
            const int ox = (c >> 2) & 1, oy = (c >> 1) & 1, oz = c & 1;
            const unsigned idx = (hx[ox] ^ hy[oy] ^ hz[oz]) & (TSZ - 1u);
            const float4 f4 = tab[l * TSZ + idx];
            const float w = wx[ox] * wy[oy] * wz[oz];
            a0 = fmaf(w, f4.x, a0); a1 = fmaf(w, f4.y, a1);
            a2 = fmaf(w, f4.z, a2); a3 = fmaf(w, f4.w, a3);
        }
        u16x4 v = { f2bf(a0), f2bf(a1), f2bf(a2), f2bf(a3) };
        *reinterpret_cast<u16x4*>(&encT[(l >> 1) * 2048 + t * 8 + (l & 1) * 4]) = v;
    }
    __syncthreads();

    f32x4 acc[4][4];
#pragma unroll
    for (int mt = 0; mt < 4; ++mt)
#pragma unroll
        for (int nt = 0; nt < 4; ++nt) acc[mt][nt] = (f32x4){0.f, 0.f, 0.f, 0.f};
#pragma unroll
    for (int kk = 0; kk < 2; ++kk) {
        bf16x8 a[4];
#pragma unroll
        for (int mt = 0; mt < 4; ++mt)
            a[mt] = *reinterpret_cast<bf16x8*>(&encT[(kk * 4 + g) * 2048 + (wv * 64 + mt * 16 + col) * 8]);
#pragma unroll
        for (int nt = 0; nt < 4; ++nt) {
            bf16x8 b = *reinterpret_cast<bf16x8*>(&w0t[(nt * 16 + col) * 64 + kk * 32 + g * 8]);
#pragma unroll
            for (int mt = 0; mt < 4; ++mt)
                acc[mt][nt] = __builtin_amdgcn_mfma_f32_16x16x32_bf16(a[mt], b, acc[mt][nt], 0, 0, 0);
        }
    }
    __syncthreads();
#pragma unroll
    for (int mt = 0; mt < 4; ++mt)
#pragma unroll
        for (int nt = 0; nt < 4; ++nt) {
            const int kt = nt * 2 + (col >> 3), j = col & 7;
#pragma unroll
            for (int r = 0; r < 4; ++r)
                encT[kt * 2048 + (wv * 64 + mt * 16 + g * 4 + r) * 8 + j] = f2bf(fmaxf(acc[mt][nt][r], 0.f));
        }
    __syncthreads();
#pragma unroll
    for (int mt = 0; mt < 4; ++mt)
#pragma unroll
        for (int nt = 0; nt < 4; ++nt) acc[mt][nt] = (f32x4){0.f, 0.f, 0.f, 0.f};
#pragma unroll
    for (int kk = 0; kk < 2; ++kk) {
        bf16x8 a[4];
#pragma unroll
        for (int mt = 0; mt < 4; ++mt)
            a[mt] = *reinterpret_cast<bf16x8*>(&encT[(kk * 4 + g) * 2048 + (wv * 64 + mt * 16 + col) * 8]);
#pragma unroll
        for (int nt = 0; nt < 4; ++nt) {
            bf16x8 b = *reinterpret_cast<bf16x8*>(&w1t[(nt * 16 + col) * 64 + kk * 32 + g * 8]);
#pragma unroll
            for (int mt = 0; mt < 4; ++mt)
                acc[mt][nt] = __builtin_amdgcn_mfma_f32_16x16x32_bf16(a[mt], b, acc[mt][nt], 0, 0, 0);
        }
    }
    __syncthreads();
#pragma unroll
    for (int mt = 0; mt < 4; ++mt)
#pragma unroll
        for (int nt = 0; nt < 4; ++nt) {
            const int kt = nt * 2 + (col >> 3), j = col & 7;
#pragma unroll
            for (int r = 0; r < 4; ++r)
                encT[kt * 2048 + (wv * 64 + mt * 16 + g * 4 + r) * 8 + j] = f2bf(fmaxf(acc[mt][nt][r], 0.f));
        }
    __syncthreads();
    f32x4 acc2[4];
#pragma unroll
    for (int mt = 0; mt < 4; ++mt) acc2[mt] = (f32x4){0.f, 0.f, 0.f, 0.f};
#pragma unroll
    for (int kk = 0; kk < 2; ++kk) {
        bf16x8 a[4];
#pragma unroll
        for (int mt = 0; mt < 4; ++mt)
            a[mt] = *reinterpret_cast<bf16x8*>(&encT[(kk * 4 + g) * 2048 + (wv * 64 + mt * 16 + col) * 8]);
        bf16x8 b = *reinterpret_cast<bf16x8*>(&w2t[col * 64 + kk * 32 + g * 8]);
#pragma unroll
        for (int mt = 0; mt < 4; ++mt)
            acc2[mt] = __builtin_amdgcn_mfma_f32_16x16x32_bf16(a[mt], b, acc2[mt], 0, 0, 0);
    }
    __syncthreads();
    float* res = reinterpret_cast<float*>(encT);
    if (col < 8) {
#pragma unroll
        for (int mt = 0; mt < 4; ++mt)
#pragma unroll
            for (int r = 0; r < 4; ++r)
                res[(wv * 64 + mt * 16 + g * 4 + r) * 8 + col] = acc2[mt][r];
    }
    __syncthreads();
    if (i < N) {
        const f32x4 lo = *reinterpret_cast<f32x4*>(&res[t * 8 + 0]);
        const f32x4 hi = *reinterpret_cast<f32x4*>(&res[t * 8 + 4]);
        out[i] = inside ? 1.f : 0.f;
        float* __restrict__ dxyz = out + N;
        dxyz[3 * i + 0] = inside ? lo.x : 0.f;
        dxyz[3 * i + 1] = inside ? lo.y : 0.f;
        dxyz[3 * i + 2] = inside ? lo.z : 0.f;
        float4* __restrict__ drot = reinterpret_cast<float4*>(out + 4 * (size_t)N);
        drot[i] = inside ? make_float4(lo.w, hi.x, hi.y, hi.z)
                         : make_float4(1.f, 0.f, 0.f, 0.f);
    }
}

extern "C" void kernel_launch(void* const* d_in, const int* in_sizes, int n_in,
                              void* d_out, int out_size, void* d_ws, size_t ws_size,
                              hipStream_t stream) {
    const float* xyz   = (const float*)d_in[0];
    const float* bmin  = (const float*)d_in[1];
    const float* bmax  = (const float*)d_in[2];
    const float* table = (const float*)d_in[3];
    const float* w0    = (const float*)d_in[4];
    const float* w1    = (const float*)d_in[5];
    const float* w2    = (const float*)d_in[6];
    float* out = (float*)d_out;

    const int N = in_sizes[0] / 3;
    const int nb = (N + 255) / 256;
    const int Npad = nb * 256;

    size_t offEnc = 14336;                         // wf8|wf1|wf2 (weights) first
    size_t need = offEnc + (size_t)Npad * 64;      // enc: 16 levels x 4B/pt

    if (ws_size >= need) {
        char* wbase   = (char*)d_ws;
        unsigned* enc = (unsigned*)((char*)d_ws + offEnc);
        k_enc<<<16 * SUBS, 1024, 0, stream>>>(xyz, bmin, bmax, table, out, enc, N, Npad,
                                              w0, w1, w2, wbase);
        k_mlp<<<nb, 256, 0, stream>>>(wbase, enc, out, N, Npad);
    } else {
        ntc_fused<<<nb, 256, 0, stream>>>(xyz, bmin, bmax, table, w0, w1, w2, out, N);
    }
}

// Round 11
// 168.803 us; speedup vs baseline: 1.1147x; 1.0272x over previous
//
#include <hip/hip_runtime.h>
#include <hip/hip_bf16.h>

// NeuralTransformationCache, 2 kernels:
//   k_enc : one level per block (16 levels x 16 sub-blocks = 256 blocks, 1/CU).
//           Converts its level slice f32->fp8(x256) while staging to LDS.
//           Block 255 packs MLP weights. Grid-stride points; enc[level][pt].
//   k_mlp : grid-stride tiles with next-tile prefetch (loads issued before
//           current tile's compute -> latency hidden). No barriers: hT and
//           resS rows are wave-private. layer0 fp8 MFMA, layers 1-2 bf16.
// Fallback fused kernel if ws too small.

#define LVL 16
#define TSZ 32768
#define PR1 2654435761u
#define PR2 805459861u
#define SUBS 16
#define STRIDE (SUBS * 1024)

typedef __attribute__((ext_vector_type(8))) short bf16x8;
typedef __attribute__((ext_vector_type(4))) float f32x4;
typedef __attribute__((ext_vector_type(2))) float f32x2;
typedef __attribute__((ext_vector_type(4))) unsigned short u16x4;
typedef __attribute__((ext_vector_type(2))) unsigned int u32x2;
typedef long long i64;

__device__ __forceinline__ unsigned short f2bf(float f) {
    return __builtin_bit_cast(unsigned short, __float2bfloat16(f));
}

// ---- fp8 e4m3fn (OCP) encode/decode, hw builtins with sw fallback ----
__device__ __forceinline__ unsigned f32x4_to_fp8x4(float f0, float f1, float f2, float f3) {
#if __has_builtin(__builtin_amdgcn_cvt_pk_fp8_f32)
    int u = 0;
    u = __builtin_amdgcn_cvt_pk_fp8_f32(f0, f1, u, false);
    u = __builtin_amdgcn_cvt_pk_fp8_f32(f2, f3, u, true);
    return (unsigned)u;
#else
    float ff[4] = { f0, f1, f2, f3 };
    unsigned u = 0;
    for (int k = 0; k < 4; ++k) {
        const float v = ff[k];
        const unsigned s = v < 0.f ? 1u : 0u;
        float av = fabsf(v);
        unsigned b;
        if (av < 6.103515625e-05f) {
            b = 0u;
        } else if (av < 0.015625f) {
            b = (unsigned)rintf(av * 512.f);
        } else {
            int e; float m = frexpf(av, &e);
            unsigned E = (unsigned)(e - 1 + 7);
            unsigned q = (unsigned)rintf(m * 16.f);
            if (q == 16u) { q = 8u; ++E; }
            b = (E << 3) | (q - 8u);
        }
        u |= ((s << 7) | b) << (8 * k);
    }
    return u;
#endif
}

__device__ __forceinline__ unsigned char f32_to_fp8(float v) {
    return (unsigned char)(f32x4_to_fp8x4(v, v, v, v) & 0xffu);
}

__device__ __forceinline__ void fp8x4_to_2f32x2(unsigned r, f32x2& lo, f32x2& hi) {
#if __has_builtin(__builtin_amdgcn_cvt_pk_f32_fp8)
    lo = __builtin_amdgcn_cvt_pk_f32_fp8((int)r, false);
    hi = __builtin_amdgcn_cvt_pk_f32_fp8((int)r, true);
#else
    float f[4];
#pragma unroll
    for (int k = 0; k < 4; ++k) {
        const unsigned b = (r >> (8 * k)) & 0xffu;
        const unsigned s = b >> 7, em = b & 0x7fu, e = em >> 3, m = em & 7u;
        float v;
        if (e) v = __builtin_bit_cast(float, ((e + 120u) << 23) | (m << 20));
        else   v = (float)m * 0.001953125f;
        f[k] = s ? -v : v;
    }
    lo = (f32x2){ f[0], f[1] };
    hi = (f32x2){ f[2], f[3] };
#endif
}

// ---------------- K1: level-per-block encode; staging converts f32->fp8 ----------------
// wbase layout (bytes): wf8[4096] (w0 fp8 frags) | wf1[8192] (w1 bf16 frags) | wf2[2048]
__global__ __launch_bounds__(1024) void k_enc(
    const float* __restrict__ xyz, const float* __restrict__ bmin, const float* __restrict__ bmax,
    const float* __restrict__ table, float* __restrict__ out,
    unsigned* __restrict__ enc, int N, int Npad,
    const float* __restrict__ w0, const float* __restrict__ w1,
    const float* __restrict__ w2, char* __restrict__ wbase)
{
    __shared__ unsigned tabL[TSZ];     // 128KB: this block's level, fp8x4 per entry

    const int t   = threadIdx.x;
    const int l   = blockIdx.x & 15;
    const int sub = blockIdx.x >> 4;

    {   // stage + convert: 512KB f32 (mostly L3-hit) -> 128KB fp8 LDS
        const float4* __restrict__ src =
            reinterpret_cast<const float4*>(table + (size_t)l * TSZ * 4);
#pragma unroll 4
        for (int j = 0; j < 32; ++j) {
            const int idx = j * 1024 + t;
            const float4 a = src[idx];
            tabL[idx] = f32x4_to_fp8x4(a.x * 256.f, a.y * 256.f, a.z * 256.f, a.w * 256.f);
        }
    }

    if (blockIdx.x == 16 * SUBS - 1 && t < 256) {
        unsigned char*  wf8 = (unsigned char*)wbase;
        unsigned short* wf1 = (unsigned short*)(wbase + 4096);
        unsigned short* wf2 = (unsigned short*)(wbase + 4096 + 8192);
#pragma unroll
        for (int q = 0; q < 16; ++q) {
            const int s = q * 256 + t;
            const int e = s & 7, f = s >> 3;
            const int ln = f & 63, ntkk = f >> 6;
            const int k = (ntkk & 1) * 32 + (ln >> 4) * 8 + e;
            const int n = (ntkk >> 1) * 16 + (ln & 15);
            wf8[s] = f32_to_fp8(w0[k * 64 + n]);
            wf1[s] = f2bf(w1[k * 64 + n]);
        }
#pragma unroll
        for (int q = 0; q < 4; ++q) {
            const int s = q * 256 + t;
            const int e = s & 7, f = s >> 3;
            const int ln = f & 63, kk = f >> 6;
            const int k = kk * 32 + (ln >> 4) * 8 + e;
            const int n = ln & 15;
            wf2[s] = (n < 8) ? f2bf(w2[k * 8 + n]) : (unsigned short)0;
        }
    }
    __syncthreads();

    const float bx0 = bmin[0], by0 = bmin[1], bz0 = bmin[2];
    const float iex = 1.f / (bmax[0] - bx0);
    const float iey = 1.f / (bmax[1] - by0);
    const float iez = 1.f / (bmax[2] - bz0);
    const float scale = 16.f * (float)(1u << l);
    unsigned* __restrict__ encL = enc + (size_t)l * Npad;
    const bool isL0 = (l == 0);

    const unsigned PR1_4 = PR1 << 2;
    const unsigned PR2_4 = PR2 << 2;
    const unsigned M2 = (TSZ - 1u) << 2;

    int p = sub * 1024 + t;
    if (p < Npad) {
        int pc = p < N ? p : N - 1;
        float cxr = xyz[3 * pc + 0], cyr = xyz[3 * pc + 1], czr = xyz[3 * pc + 2];

        for (; p < Npad; ) {
            const int pn  = p + STRIDE;
            const int pnc = (pn < N) ? pn : (N - 1);
            const float nxr = xyz[3 * pnc + 0];
            const float nyr = xyz[3 * pnc + 1];
            const float nzr = xyz[3 * pnc + 2];

            const float ccx = (cxr - bx0) * iex;
            const float ccy = (cyr - by0) * iey;
            const float ccz = (czr - bz0) * iez;
            if (isL0 && p < N) {
                const bool inside = (ccx >= 0.f) && (ccx <= 1.f) && (ccy >= 0.f) &&
                                    (ccy <= 1.f) && (ccz >= 0.f) && (ccz <= 1.f);
                out[p] = inside ? 1.f : 0.f;
            }
            const float x = fminf(fmaxf(ccx, 0.f), 1.f);
            const float y = fminf(fmaxf(ccy, 0.f), 1.f);
            const float z = fminf(fmaxf(ccz, 0.f), 1.f);

            const float px = x * scale, py = y * scale, pz = z * scale;
            const float fx = floorf(px), fy = floorf(py), fz = floorf(pz);
            const float rx = px - fx, ry = py - fy, rz = pz - fz;
            const unsigned ux = (unsigned)fx, uy = (unsigned)fy, uz = (unsigned)fz;

            const unsigned ux4 = ux << 2;
            const unsigned hy4 = uy * PR1_4, hz4 = uz * PR2_4;
            const unsigned hxy2[4] = {
                (ux4        ^ hy4)           & M2,
                (ux4        ^ (hy4 + PR1_4)) & M2,
                ((ux4 + 4u) ^ hy4)           & M2,
                ((ux4 + 4u) ^ (hy4 + PR1_4)) & M2 };
            const unsigned hz2[2] = { hz4 & M2, (hz4 + PR2_4) & M2 };

            const float wx0 = 1.f - rx, wy0 = 1.f - ry, wz0 = 1.f - rz;
            const f32x2 wyp = { wy0, ry };
            const f32x2 wxyA = (f32x2){ wx0, wx0 } * wyp;
            const f32x2 wxyB = (f32x2){ rx,  rx  } * wyp;
            const f32x2 wz2 = { wz0, rz };
            const f32x2 w8[4] = {
                (f32x2){ wxyA[0], wxyA[0] } * wz2,
                (f32x2){ wxyA[1], wxyA[1] } * wz2,
                (f32x2){ wxyB[0], wxyB[0] } * wz2,
                (f32x2){ wxyB[1], wxyB[1] } * wz2 };

            unsigned r[8];
#pragma unroll
            for (int c = 0; c < 8; ++c)
                r[c] = *reinterpret_cast<const unsigned*>(
                    reinterpret_cast<const char*>(tabL) + (hxy2[c >> 1] ^ hz2[c & 1]));

            f32x2 a01 = { 0.f, 0.f }, a23 = { 0.f, 0.f };
#pragma unroll
            for (int c = 0; c < 8; ++c) {
                f32x2 lo, hi;
                fp8x4_to_2f32x2(r[c], lo, hi);
                const float w = w8[c >> 1][c & 1];
                const f32x2 w2 = { w, w };
                a01 += w2 * lo;
                a23 += w2 * hi;
            }

            const unsigned v = f32x4_to_fp8x4(a01[0], a01[1], a23[0], a23[1]);
            __builtin_nontemporal_store(v, encL + p);

            p = pn; cxr = nxr; cyr = nyr; czr = nzr;
        }
    }
}

// ---------------- K2: MLP — grid-stride tiles, next-tile prefetch, no barriers ----------------
__global__ __launch_bounds__(256) void k_mlp(
    const char* __restrict__ wbase, const unsigned* __restrict__ enc,
    float* __restrict__ out, int N, int Npad, int nb)
{
    __shared__ unsigned short hT[8 * 256 * 8];  // 32KB, wave-private rows
    __shared__ float resS[256 * 8];             // 8KB,  wave-private rows

    const unsigned char*  wf8 = (const unsigned char*)wbase;
    const unsigned short* wf1 = (const unsigned short*)(wbase + 4096);
    const unsigned short* wf2 = (const unsigned short*)(wbase + 4096 + 8192);

    const int t = threadIdx.x, wv = t >> 6, ln = t & 63;
    const int col = ln & 15, g = ln >> 4;

    // resident B fragments: b0 (L0 fp8, 8 VGPR) + b2 (L2 bf16, 8 VGPR)
    u32x2 b0[4][2];
#pragma unroll
    for (int nt = 0; nt < 4; ++nt)
#pragma unroll
        for (int kk = 0; kk < 2; ++kk)
            b0[nt][kk] = *reinterpret_cast<const u32x2*>(wf8 + ((nt * 2 + kk) * 64 + ln) * 8);
    bf16x8 b2f[2];
#pragma unroll
    for (int kk = 0; kk < 2; ++kk)
        b2f[kk] = *reinterpret_cast<const bf16x8*>(wf2 + (kk * 64 + ln) * 8);

    int tile = blockIdx.x;
    if (tile >= nb) return;

    // current tile A0 fragments + mask (prefetched)
    u32x2 aC[2][4];
    {
        const int ptb = tile * 256;
#pragma unroll
        for (int kk = 0; kk < 2; ++kk)
#pragma unroll
            for (int mt = 0; mt < 4; ++mt) {
                const size_t pt = (size_t)ptb + wv * 64 + mt * 16 + col;
                const int j = kk * 4 + g;
                u32x2 a;
                a[0] = __builtin_nontemporal_load(enc + (size_t)(2 * j)     * Npad + pt);
                a[1] = __builtin_nontemporal_load(enc + (size_t)(2 * j + 1) * Npad + pt);
                aC[kk][mt] = a;
            }
    }
    float mkC = 0.f;
    { const int i0 = tile * 256 + t; if (i0 < N) mkC = out[i0]; }

    for (;;) {
        const int tn = tile + (int)gridDim.x;
        const bool more = (tn < nb);

        // ---- issue next tile's loads FIRST (latency hides under compute) ----
        u32x2 aN[2][4];
        float mkN = 0.f;
        if (more) {
            const int ptb = tn * 256;
#pragma unroll
            for (int kk = 0; kk < 2; ++kk)
#pragma unroll
                for (int mt = 0; mt < 4; ++mt) {
                    const size_t pt = (size_t)ptb + wv * 64 + mt * 16 + col;
                    const int j = kk * 4 + g;
                    u32x2 a;
                    a[0] = __builtin_nontemporal_load(enc + (size_t)(2 * j)     * Npad + pt);
                    a[1] = __builtin_nontemporal_load(enc + (size_t)(2 * j + 1) * Npad + pt);
                    aN[kk][mt] = a;
                }
            const int i1 = tn * 256 + t; if (i1 < N) mkN = out[i1];
        }
        // b1 per tile (L1-hot after first iteration)
        bf16x8 b1[4][2];
#pragma unroll
        for (int nt = 0; nt < 4; ++nt)
#pragma unroll
            for (int kk = 0; kk < 2; ++kk)
                b1[nt][kk] = *reinterpret_cast<const bf16x8*>(wf1 + ((nt * 2 + kk) * 64 + ln) * 8);

        // ---- layer 0 (fp8 MFMA) ----
        f32x4 acc[4][4];
#pragma unroll
        for (int mt = 0; mt < 4; ++mt)
#pragma unroll
            for (int nt = 0; nt < 4; ++nt) acc[mt][nt] = (f32x4){0.f, 0.f, 0.f, 0.f};

#pragma unroll
        for (int kk = 0; kk < 2; ++kk)
#pragma unroll
            for (int nt = 0; nt < 4; ++nt)
#pragma unroll
                for (int mt = 0; mt < 4; ++mt)
                    acc[mt][nt] = __builtin_amdgcn_mfma_f32_16x16x32_fp8_fp8(
                        __builtin_bit_cast(i64, aC[kk][mt]),
                        __builtin_bit_cast(i64, b0[nt][kk]), acc[mt][nt], 0, 0, 0);

        // relu + 1/256 -> hT (wave-private rows; in-wave lgkmcnt ordering suffices)
#pragma unroll
        for (int mt = 0; mt < 4; ++mt)
#pragma unroll
            for (int nt = 0; nt < 4; ++nt) {
                const int kt = nt * 2 + (col >> 3), j = col & 7;
#pragma unroll
                for (int r = 0; r < 4; ++r)
                    hT[kt * 2048 + (wv * 64 + mt * 16 + g * 4 + r) * 8 + j] =
                        f2bf(fmaxf(acc[mt][nt][r], 0.f) * 0.00390625f);
            }

        // ---- layer 1 (bf16) ----
#pragma unroll
        for (int mt = 0; mt < 4; ++mt)
#pragma unroll
            for (int nt = 0; nt < 4; ++nt) acc[mt][nt] = (f32x4){0.f, 0.f, 0.f, 0.f};

#pragma unroll
        for (int kk = 0; kk < 2; ++kk) {
            bf16x8 a[4];
#pragma unroll
            for (int mt = 0; mt < 4; ++mt)
                a[mt] = *reinterpret_cast<bf16x8*>(
                    &hT[(kk * 4 + g) * 2048 + (wv * 64 + mt * 16 + col) * 8]);
#pragma unroll
            for (int nt = 0; nt < 4; ++nt)
#pragma unroll
                for (int mt = 0; mt < 4; ++mt)
                    acc[mt][nt] = __builtin_amdgcn_mfma_f32_16x16x32_bf16(a[mt], b1[nt][kk], acc[mt][nt], 0, 0, 0);
        }

#pragma unroll
        for (int mt = 0; mt < 4; ++mt)
#pragma unroll
            for (int nt = 0; nt < 4; ++nt) {
                const int kt = nt * 2 + (col >> 3), j = col & 7;
#pragma unroll
                for (int r = 0; r < 4; ++r)
                    hT[kt * 2048 + (wv * 64 + mt * 16 + g * 4 + r) * 8 + j] =
                        f2bf(fmaxf(acc[mt][nt][r], 0.f));
            }

        // ---- layer 2 (bf16) ----
        f32x4 acc2[4];
#pragma unroll
        for (int mt = 0; mt < 4; ++mt) acc2[mt] = (f32x4){0.f, 0.f, 0.f, 0.f};

#pragma unroll
        for (int kk = 0; kk < 2; ++kk) {
            bf16x8 a[4];
#pragma unroll
            for (int mt = 0; mt < 4; ++mt)
                a[mt] = *reinterpret_cast<bf16x8*>(
                    &hT[(kk * 4 + g) * 2048 + (wv * 64 + mt * 16 + col) * 8]);
#pragma unroll
            for (int mt = 0; mt < 4; ++mt)
                acc2[mt] = __builtin_amdgcn_mfma_f32_16x16x32_bf16(a[mt], b2f[kk], acc2[mt], 0, 0, 0);
        }

        // resS transpose (wave-private rows -> no barrier needed)
        if (col < 8) {
#pragma unroll
            for (int mt = 0; mt < 4; ++mt)
#pragma unroll
                for (int r = 0; r < 4; ++r)
                    resS[(wv * 64 + mt * 16 + g * 4 + r) * 8 + col] = acc2[mt][r];
        }

        const int i = tile * 256 + t;
        if (i < N) {
            const bool inside = (mkC != 0.f);
            const f32x4 lo = *reinterpret_cast<f32x4*>(&resS[t * 8 + 0]);
            const f32x4 hi = *reinterpret_cast<f32x4*>(&resS[t * 8 + 4]);

            float* __restrict__ dxyz = out + N;
            dxyz[3 * i + 0] = inside ? lo.x : 0.f;
            dxyz[3 * i + 1] = inside ? lo.y : 0.f;
            dxyz[3 * i + 2] = inside ? lo.z : 0.f;

            float4* __restrict__ drot = reinterpret_cast<float4*>(out + 4 * (size_t)N);
            drot[i] = inside ? make_float4(lo.w, hi.x, hi.y, hi.z)
                             : make_float4(1.f, 0.f, 0.f, 0.f);
        }

        if (!more) break;
#pragma unroll
        for (int kk = 0; kk < 2; ++kk)
#pragma unroll
            for (int mt = 0; mt < 4; ++mt) aC[kk][mt] = aN[kk][mt];
        mkC = mkN;
        tile = tn;
    }
}

// ---------------- Fallback: fused kernel (only if ws too small) ----------------
__global__ __launch_bounds__(256) void ntc_fused(
    const float* __restrict__ xyz, const float* __restrict__ bmin, const float* __restrict__ bmax,
    const float* __restrict__ table, const float* __restrict__ w0, const float* __restrict__ w1,
    const float* __restrict__ w2, float* __restrict__ out, int N)
{
    __shared__ unsigned short encT[8 * 256 * 8];
    __shared__ unsigned short w0t[64 * 64];
    __shared__ unsigned short w1t[64 * 64];
    __shared__ unsigned short w2t[16 * 64];

    const int t = threadIdx.x, wv = t >> 6, ln = t & 63;
    const int col = ln & 15, g = ln >> 4;

#pragma unroll
    for (int it = 0; it < 16; ++it) {
        const int idx = it * 256 + t;
        const int k = idx >> 6, n = idx & 63;
        w0t[n * 64 + k] = f2bf(w0[idx]);
        w1t[n * 64 + k] = f2bf(w1[idx]);
    }
#pragma unroll
    for (int q = 0; q < 4; ++q) {
        const int idx = t * 4 + q;
        const int n = idx >> 6, k = idx & 63;
        w2t[idx] = (n < 8) ? f2bf(w2[k * 8 + n]) : (unsigned short)0;
    }

    const int i = blockIdx.x * 256 + t;
    const int ic = (i < N) ? i : (N - 1);
    const float bx0 = bmin[0], by0 = bmin[1], bz0 = bmin[2];
    const float ex = bmax[0] - bx0, ey = bmax[1] - by0, ez = bmax[2] - bz0;
    const float cx = (xyz[3 * ic + 0] - bx0) / ex;
    const float cy = (xyz[3 * ic + 1] - by0) / ey;
    const float cz = (xyz[3 * ic + 2] - bz0) / ez;
    const bool inside = (cx >= 0.f) && (cx <= 1.f) && (cy >= 0.f) && (cy <= 1.f) &&
                        (cz >= 0.f) && (cz <= 1.f);
    const float x = fminf(fmaxf(cx, 0.f), 1.f);
    const float y = fminf(fmaxf(cy, 0.f), 1.f);
    const float z = fminf(fmaxf(cz, 0.f), 1.f);
    const float4* __restrict__ tab = reinterpret_cast<const float4*>(table);

    for (int l = 0; l < LVL; ++l) {
        const float scale = 16.f * (float)(1u << l);
        const float px = x * scale, py = y * scale, pz = z * scale;
        const float fx = floorf(px), fy = floorf(py), fz = floorf(pz);
        const float rx = px - fx, ry = py - fy, rz = pz - fz;
        const unsigned ux = (unsigned)fx, uy = (unsigned)fy, uz = (unsigned)fz;
        const unsigned hx[2] = { ux, ux + 1u };
        const unsigned hy[2] = { uy * PR1, (uy + 1u) * PR1 };
        const unsigned hz[2] = { uz * PR2, (uz + 1u) * PR2 };
        const float wx[2] = { 1.f - rx, rx };
        const float wy[2] = { 1.f - ry, ry };
        const float wz[2] = { 1.f - rz, rz };
        float a0 = 0.f, a1 = 0.f, a2 = 0.f, a3 = 0.f;
#pragma unroll
        for (int c = 0; c < 8; ++c) {
            const int ox = (c >> 2) & 1, oy = (c >> 1) & 1, oz = c & 1;
            const unsigned idx = (hx[ox] ^ hy[oy] ^ hz[oz]) & (TSZ - 1u);
            const float4 f4 = tab[l * TSZ + idx];
            const float w = wx[ox] * wy[oy] * wz[oz];
            a0 = fmaf(w, f4.x, a0); a1 = fmaf(w, f4.y, a1);
            a2 = fmaf(w, f4.z, a2); a3 = fmaf(w, f4.w, a3);
        }
        u16x4 v = { f2bf(a0), f2bf(a1), f2bf(a2), f2bf(a3) };
        *reinterpret_cast<u16x4*>(&encT[(l >> 1) * 2048 + t * 8 + (l & 1) * 4]) = v;
    }
    __syncthreads();

    f32x4 acc[4][4];
#pragma unroll
    for (int mt = 0; mt < 4; ++mt)
#pragma unroll
        for (int nt = 0; nt < 4; ++nt) acc[mt][nt] = (f32x4){0.f, 0.f, 0.f, 0.f};
#pragma unroll
    for (int kk = 0; kk < 2; ++kk) {
        bf16x8 a[4];
#pragma unroll
        for (int mt = 0; mt < 4; ++mt)
            a[mt] = *reinterpret_cast<bf16x8*>(&encT[(kk * 4 + g) * 2048 + (wv * 64 + mt * 16 + col) * 8]);
#pragma unroll
        for (int nt = 0; nt < 4; ++nt) {
            bf16x8 b = *reinterpret_cast<bf16x8*>(&w0t[(nt * 16 + col) * 64 + kk * 32 + g * 8]);
#pragma unroll
            for (int mt = 0; mt < 4; ++mt)
                acc[mt][nt] = __builtin_amdgcn_mfma_f32_16x16x32_bf16(a[mt], b, acc[mt][nt], 0, 0, 0);
        }
    }
    __syncthreads();
#pragma unroll
    for (int mt = 0; mt < 4; ++mt)
#pragma unroll
        for (int nt = 0; nt < 4; ++nt) {
            const int kt = nt * 2 + (col >> 3), j = col & 7;
#pragma unroll
            for (int r = 0; r < 4; ++r)
                encT[kt * 2048 + (wv * 64 + mt * 16 + g * 4 + r) * 8 + j] = f2bf(fmaxf(acc[mt][nt][r], 0.f));
        }
    __syncthreads();
#pragma unroll
    for (int mt = 0; mt < 4; ++mt)
#pragma unroll
        for (int nt = 0; nt < 4; ++nt) acc[mt][nt] = (f32x4){0.f, 0.f, 0.f, 0.f};
#pragma unroll
    for (int kk = 0; kk < 2; ++kk) {
        bf16x8 a[4];
#pragma unroll
        for (int mt = 0; mt < 4; ++mt)
            a[mt] = *reinterpret_cast<bf16x8*>(&encT[(kk * 4 + g) * 2048 + (wv * 64 + mt * 16 + col) * 8]);
#pragma unroll
        for (int nt = 0; nt < 4; ++nt) {
            bf16x8 b = *reinterpret_cast<bf16x8*>(&w1t[(nt * 16 + col) * 64 + kk * 32 + g * 8]);
#pragma unroll
            for (int mt = 0; mt < 4; ++mt)
                acc[mt][nt] = __builtin_amdgcn_mfma_f32_16x16x32_bf16(a[mt], b, acc[mt][nt], 0, 0, 0);
        }
    }
    __syncthreads();
#pragma unroll
    for (int mt = 0; mt < 4; ++mt)
#pragma unroll
        for (int nt = 0; nt < 4; ++nt) {
            const int kt = nt * 2 + (col >> 3), j = col & 7;
#pragma unroll
            for (int r = 0; r < 4; ++r)
                encT[kt * 2048 + (wv * 64 + mt * 16 + g * 4 + r) * 8 + j] = f2bf(fmaxf(acc[mt][nt][r], 0.f));
        }
    __syncthreads();
    f32x4 acc2[4];
#pragma unroll
    for (int mt = 0; mt < 4; ++mt) acc2[mt] = (f32x4){0.f, 0.f, 0.f, 0.f};
#pragma unroll
    for (int kk = 0; kk < 2; ++kk) {
        bf16x8 a[4];
#pragma unroll
        for (int mt = 0; mt < 4; ++mt)
            a[mt] = *reinterpret_cast<bf16x8*>(&encT[(kk * 4 + g) * 2048 + (wv * 64 + mt * 16 + col) * 8]);
        bf16x8 b = *reinterpret_cast<bf16x8*>(&w2t[col * 64 + kk * 32 + g * 8]);
#pragma unroll
        for (int mt = 0; mt < 4; ++mt)
            acc2[mt] = __builtin_amdgcn_mfma_f32_16x16x32_bf16(a[mt], b, acc2[mt], 0, 0, 0);
    }
    __syncthreads();
    float* res = reinterpret_cast<float*>(encT);
    if (col < 8) {
#pragma unroll
        for (int mt = 0; mt < 4; ++mt)
#pragma unroll
            for (int r = 0; r < 4; ++r)
                res[(wv * 64 + mt * 16 + g * 4 + r) * 8 + col] = acc2[mt][r];
    }
    __syncthreads();
    if (i < N) {
        const f32x4 lo = *reinterpret_cast<f32x4*>(&res[t * 8 + 0]);
        const f32x4 hi = *reinterpret_cast<f32x4*>(&res[t * 8 + 4]);
        out[i] = inside ? 1.f : 0.f;
        float* __restrict__ dxyz = out + N;
        dxyz[3 * i + 0] = inside ? lo.x : 0.f;
        dxyz[3 * i + 1] = inside ? lo.y : 0.f;
        dxyz[3 * i + 2] = inside ? lo.z : 0.f;
        float4* __restrict__ drot = reinterpret_cast<float4*>(out + 4 * (size_t)N);
        drot[i] = inside ? make_float4(lo.w, hi.x, hi.y, hi.z)
                         : make_float4(1.f, 0.f, 0.f, 0.f);
    }
}

extern "C" void kernel_launch(void* const* d_in, const int* in_sizes, int n_in,
                              void* d_out, int out_size, void* d_ws, size_t ws_size,
                              hipStream_t stream) {
    const float* xyz   = (const float*)d_in[0];
    const float* bmin  = (const float*)d_in[1];
    const float* bmax  = (const float*)d_in[2];
    const float* table = (const float*)d_in[3];
    const float* w0    = (const float*)d_in[4];
    const float* w1    = (const float*)d_in[5];
    const float* w2    = (const float*)d_in[6];
    float* out = (float*)d_out;

    const int N = in_sizes[0] / 3;
    const int nb = (N + 255) / 256;
    const int Npad = nb * 256;

    size_t offEnc = 14336;
    size_t need = offEnc + (size_t)Npad * 64;

    if (ws_size >= need) {
        char* wbase   = (char*)d_ws;
        unsigned* enc = (unsigned*)((char*)d_ws + offEnc);
        const int nbK = nb < 1024 ? nb : 1024;
        k_enc<<<16 * SUBS, 1024, 0, stream>>>(xyz, bmin, bmax, table, out, enc, N, Npad,
                                              w0, w1, w2, wbase);
        k_mlp<<<nbK, 256, 0, stream>>>(wbase, enc, out, N, Npad, nb);
    } else {
        ntc_fused<<<nb, 256, 0, stream>>>(xyz, bmin, bmax, table, w0, w1, w2, out, N);
    }
}